// Round 2
// baseline (4339.978 us; speedup 1.0000x reference)
//
#include <hip/hip_runtime.h>
#include <hip/hip_bf16.h>
#include <stdint.h>
#include <stddef.h>

#define NPTS 8192
#define KNN  12
#define CH   128
#define FFD  512
#define MEDGE (NPTS * KNN)   // 98304 edges

typedef __attribute__((ext_vector_type(8))) _Float16 half8;
typedef __attribute__((ext_vector_type(4))) float f32x4;

__device__ __forceinline__ float wave_sum(float v) {
#pragma unroll
  for (int off = 32; off > 0; off >>= 1) v += __shfl_xor(v, off, 64);
  return v;
}
__device__ __forceinline__ float sigm_(float x) { return 1.0f / (1.0f + expf(-x)); }
__device__ __forceinline__ float gelu_(float x) { return 0.5f * x * (1.0f + erff(x * 0.7071067811865475f)); }

// ---------------------------------------------------------------------------
// KNN (stable top-12 by (dist, idx)) + RBF embed  -> nbr [N,K], v0 [N,K,C] f32
// ---------------------------------------------------------------------------
__global__ __launch_bounds__(256)
void knn_embed(const float* __restrict__ coords, int* __restrict__ nbr, float* __restrict__ v0)
{
#pragma clang fp contract(off)
  __shared__ unsigned long long red[256];
  __shared__ unsigned long long sel[KNN];
  const int i = blockIdx.x;
  const int tid = threadIdx.x;
  const float cx = coords[3 * i + 0];
  const float cy = coords[3 * i + 1];
  const float cz = coords[3 * i + 2];
  unsigned long long best[KNN];
#pragma unroll
  for (int q = 0; q < KNN; ++q) best[q] = ~0ULL;
  for (int j = tid; j < NPTS; j += 256) {
    float dx = cx - coords[3 * j + 0];
    float dy = cy - coords[3 * j + 1];
    float dz = cz - coords[3 * j + 2];
    float d2 = dx * dx + dy * dy + dz * dz;   // contract off: matches numpy order
    float d = sqrtf(d2);
    unsigned long long key = (((unsigned long long)__float_as_uint(d)) << 32) | (unsigned int)j;
    if (key < best[KNN - 1]) {
      best[KNN - 1] = key;
#pragma unroll
      for (int q = KNN - 2; q >= 0; --q) {
        if (best[q + 1] < best[q]) { unsigned long long t = best[q]; best[q] = best[q + 1]; best[q + 1] = t; }
      }
    }
  }
  // merge 256 sorted lists -> global top-12 (stable; keys unique)
  int p = 0;
  for (int r = 0; r < KNN; ++r) {
    unsigned long long c = ~0ULL;
#pragma unroll
    for (int q = 0; q < KNN; ++q) if (q == p) c = best[q];
    red[tid] = c;
    __syncthreads();
    for (int s = 128; s > 0; s >>= 1) {
      if (tid < s) { unsigned long long o = red[tid + s]; if (o < red[tid]) red[tid] = o; }
      __syncthreads();
    }
    unsigned long long mn = red[0];
    if (c == mn) ++p;
    if (tid == 0) sel[r] = mn;
    __syncthreads();
  }
  if (tid < KNN) nbr[i * KNN + tid] = (int)(unsigned int)(sel[tid] & 0xFFFFFFFFULL);
  for (int idx = tid; idx < KNN * CH; idx += 256) {
    int k = idx >> 7, ch = idx & 127;
    float d = __uint_as_float((unsigned int)(sel[k] >> 32));
    float sig = (float)(1.0 + 4.0 * (double)ch / 127.0);     // linspace(1,5,128)
    float g = expf((-(d * d)) / (2.0f * (sig * sig)));
    v0[(size_t)(i * KNN + k) * CH + ch] = (g > 0.1f) ? g : 0.0f;
  }
}

// ---------------------------------------------------------------------------
// transpose index: tidx[i*K+k] = j*K+pos where nbr[j,pos]==i, else -1
// ---------------------------------------------------------------------------
__global__ __launch_bounds__(256)
void build_tidx(const int* __restrict__ nbr, int* __restrict__ tidx)
{
  int e = blockIdx.x * 256 + threadIdx.x;
  if (e >= MEDGE) return;
  int i = e / KNN;
  int j = nbr[e];
  int res = -1;
#pragma unroll
  for (int t = 0; t < KNN; ++t) {
    if (nbr[j * KNN + t] == i) { res = j * KNN + t; break; }
  }
  tidx[e] = res;
}

// ---------------------------------------------------------------------------
// weight transpose + fp16 cast: dst[b][c][r] = f16(src[b][r][c])
// ---------------------------------------------------------------------------
__global__ __launch_bounds__(256)
void transpose_cast(const float* __restrict__ src, _Float16* __restrict__ dst,
                    int B, int R, int C2)
{
  int total = B * R * C2;
  int idx = blockIdx.x * 256 + threadIdx.x;
  if (idx >= total) return;
  int b = idx / (R * C2);
  int rem = idx - b * (R * C2);
  int c = rem / R;
  int r = rem - c * R;
  dst[idx] = (_Float16)(src[((size_t)b * R + r) * C2 + c]);
}

// ---------------------------------------------------------------------------
// shared helpers for MFMA tiles
// ---------------------------------------------------------------------------
__device__ __forceinline__ void stage_w(const _Float16* __restrict__ src, int srcStride,
                                        _Float16 (*dst)[136], int tid)
{
#pragma unroll
  for (int it = 0; it < 8; ++it) {
    int chunk = tid + it * 256;          // 2048 chunks of 8 f16
    int row = chunk >> 4;
    int ko = (chunk & 15) * 8;
    *(half8*)&dst[row][ko] = *(const half8*)(src + (size_t)row * srcStride + ko);
  }
}

__device__ __forceinline__ void mm8_lds(const half8 xf[4], const _Float16 (*ws_)[136],
                                        int l16, int quad, f32x4 acc[8])
{
#pragma unroll
  for (int nt = 0; nt < 8; ++nt) {
    f32x4 a = {0.0f, 0.0f, 0.0f, 0.0f};
#pragma unroll
    for (int kt = 0; kt < 4; ++kt) {
      half8 wf = *(const half8*)&ws_[nt * 16 + l16][kt * 32 + quad * 8];
      a = __builtin_amdgcn_mfma_f32_16x16x32_f16(xf[kt], wf, a, 0, 0, 0);
    }
    acc[nt] = a;
  }
}

// LN of one 128-wide row -> fp16 LDS row (wave-cooperative)
__device__ __forceinline__ void ln_row(const float* __restrict__ vp, float g1, float g2,
                                       float b1, float b2, _Float16* dst, int lane)
{
  float x1 = vp[lane], x2 = vp[lane + 64];
  float m = wave_sum(x1 + x2) * (1.0f / 128.0f);
  float d1 = x1 - m, d2 = x2 - m;
  float var = wave_sum(d1 * d1 + d2 * d2) * (1.0f / 128.0f);
  float rs = 1.0f / sqrtf(var + 1e-5f);
  dst[lane]      = (_Float16)(d1 * rs * g1 + b1);
  dst[lane + 64] = (_Float16)(d2 * rs * g2 + b2);
}

// ---------------------------------------------------------------------------
// LN(v) -> a = sig(x@Wga+bga)*(x@Wa+ba), b = ..., go = sig(x@Wgo+bgo)  (f16)
// ---------------------------------------------------------------------------
__global__ __launch_bounds__(256)
void ln_gemm5(const float* __restrict__ vin,
              const float* __restrict__ ln_g, const float* __restrict__ ln_b,
              const _Float16* __restrict__ wtA,  const float* __restrict__ bA,
              const _Float16* __restrict__ wtGA, const float* __restrict__ bGA,
              const _Float16* __restrict__ wtB,  const float* __restrict__ bB,
              const _Float16* __restrict__ wtGB, const float* __restrict__ bGB,
              const _Float16* __restrict__ wtGO, const float* __restrict__ bGO,
              _Float16* __restrict__ aout, _Float16* __restrict__ bout,
              _Float16* __restrict__ goout)
{
  __shared__ alignas(16) _Float16 xs[64][136];
  __shared__ alignas(16) _Float16 ws_[128][136];
  const int tid = threadIdx.x;
  const int lane = tid & 63;
  const int w = tid >> 6;
  const int quad = lane >> 4;
  const int l16 = lane & 15;
  const int rowBase = blockIdx.x * 64;

  float gg1 = ln_g[lane], gg2 = ln_g[lane + 64];
  float gb1 = ln_b[lane], gb2 = ln_b[lane + 64];
  for (int r = 0; r < 16; ++r) {
    int row = w * 16 + r;
    ln_row(vin + (size_t)(rowBase + row) * CH, gg1, gg2, gb1, gb2, &xs[row][0], lane);
  }
  __syncthreads();
  stage_w(wtA, CH, ws_, tid);
  __syncthreads();

  half8 xf[4];
#pragma unroll
  for (int kt = 0; kt < 4; ++kt)
    xf[kt] = *(const half8*)&xs[w * 16 + l16][kt * 32 + quad * 8];

  const int rowq = w * 16 + quad * 4;
  f32x4 accP[8], accQ[8];

  // ---- a ----
  mm8_lds(xf, ws_, l16, quad, accP);
  __syncthreads();
  stage_w(wtGA, CH, ws_, tid);
  __syncthreads();
  mm8_lds(xf, ws_, l16, quad, accQ);
#pragma unroll
  for (int nt = 0; nt < 8; ++nt) {
    int col = nt * 16 + l16;
    float bv = bA[col], bgv = bGA[col];
#pragma unroll
    for (int r = 0; r < 4; ++r) {
      float ya = accP[nt][r] + bv;
      float yg = accQ[nt][r] + bgv;
      aout[(size_t)(rowBase + rowq + r) * CH + col] = (_Float16)(sigm_(yg) * ya);
    }
  }
  // ---- b ----
  __syncthreads();
  stage_w(wtB, CH, ws_, tid);
  __syncthreads();
  mm8_lds(xf, ws_, l16, quad, accP);
  __syncthreads();
  stage_w(wtGB, CH, ws_, tid);
  __syncthreads();
  mm8_lds(xf, ws_, l16, quad, accQ);
#pragma unroll
  for (int nt = 0; nt < 8; ++nt) {
    int col = nt * 16 + l16;
    float bv = bB[col], bgv = bGB[col];
#pragma unroll
    for (int r = 0; r < 4; ++r) {
      float yb = accP[nt][r] + bv;
      float yg = accQ[nt][r] + bgv;
      bout[(size_t)(rowBase + rowq + r) * CH + col] = (_Float16)(sigm_(yg) * yb);
    }
  }
  // ---- go ----
  __syncthreads();
  stage_w(wtGO, CH, ws_, tid);
  __syncthreads();
  mm8_lds(xf, ws_, l16, quad, accP);
#pragma unroll
  for (int nt = 0; nt < 8; ++nt) {
    int col = nt * 16 + l16;
    float bgv = bGO[col];
#pragma unroll
    for (int r = 0; r < 4; ++r)
      goout[(size_t)(rowBase + rowq + r) * CH + col] = (_Float16)(sigm_(accP[nt][r] + bgv));
  }
}

// ---------------------------------------------------------------------------
// sparse triangle einsum: k[n,m,c] = sum_t A(n,t,c) * B(nbr[n,m],t,c)
// incoming=1: A/B read through transpose index (0 if absent)
// ---------------------------------------------------------------------------
__global__ __launch_bounds__(256)
void tri_einsum(const _Float16* __restrict__ a, const _Float16* __restrict__ b,
                const int* __restrict__ nbr, const int* __restrict__ tidx,
                float* __restrict__ kout, int incoming)
{
  __shared__ float As[KNN][CH];
  __shared__ int bidx[KNN][KNN];
  __shared__ int nbr_s[KNN];
  const int n = blockIdx.x;
  const int tid = threadIdx.x;
  if (tid < KNN) nbr_s[tid] = nbr[n * KNN + tid];
  __syncthreads();
  if (tid < KNN * KNN) {
    int m = tid / KNN, t = tid - m * KNN;
    int j = nbr_s[m];
    bidx[m][t] = incoming ? tidx[j * KNN + t] : (j * KNN + t);
  }
  for (int idx = tid; idx < KNN * CH; idx += 256) {
    int t = idx >> 7, c = idx & 127;
    float av;
    if (incoming) {
      int ti = tidx[n * KNN + t];
      av = (ti >= 0) ? (float)(a[(size_t)ti * CH + c]) : 0.0f;
    } else {
      av = (float)(a[(size_t)(n * KNN + t) * CH + c]);
    }
    As[t][c] = av;
  }
  __syncthreads();
  const int c = tid & 127;
  const int mh = tid >> 7;
  for (int mm = 0; mm < 6; ++mm) {
    int m = mm * 2 + mh;
    float acc = 0.0f;
#pragma unroll
    for (int t = 0; t < KNN; ++t) {
      int bi = bidx[m][t];
      float bv = (bi >= 0) ? (float)(b[(size_t)bi * CH + c]) : 0.0f;
      acc += As[t][c] * bv;
    }
    kout[(size_t)(n * KNN + m) * CH + c] = acc;
  }
}

// ---------------------------------------------------------------------------
// v += go * (LN(k) @ Wo + bo)
// ---------------------------------------------------------------------------
__global__ __launch_bounds__(256)
void ln_out_gate(const float* __restrict__ kin,
                 const float* __restrict__ ln_g, const float* __restrict__ ln_b,
                 const _Float16* __restrict__ wtO, const float* __restrict__ bO,
                 const _Float16* __restrict__ goin, float* __restrict__ vio)
{
  __shared__ alignas(16) _Float16 xs[64][136];
  __shared__ alignas(16) _Float16 ws_[128][136];
  const int tid = threadIdx.x;
  const int lane = tid & 63;
  const int w = tid >> 6;
  const int quad = lane >> 4;
  const int l16 = lane & 15;
  const int rowBase = blockIdx.x * 64;

  float gg1 = ln_g[lane], gg2 = ln_g[lane + 64];
  float gb1 = ln_b[lane], gb2 = ln_b[lane + 64];
  for (int r = 0; r < 16; ++r) {
    int row = w * 16 + r;
    ln_row(kin + (size_t)(rowBase + row) * CH, gg1, gg2, gb1, gb2, &xs[row][0], lane);
  }
  __syncthreads();
  stage_w(wtO, CH, ws_, tid);
  __syncthreads();

  half8 xf[4];
#pragma unroll
  for (int kt = 0; kt < 4; ++kt)
    xf[kt] = *(const half8*)&xs[w * 16 + l16][kt * 32 + quad * 8];

  f32x4 acc[8];
  mm8_lds(xf, ws_, l16, quad, acc);
  const int rowq = w * 16 + quad * 4;
#pragma unroll
  for (int nt = 0; nt < 8; ++nt) {
    int col = nt * 16 + l16;
    float bv = bO[col];
#pragma unroll
    for (int r = 0; r < 4; ++r) {
      size_t off = (size_t)(rowBase + rowq + r) * CH + col;
      vio[off] += (float)(goin[off]) * (acc[nt][r] + bv);
    }
  }
}

// ---------------------------------------------------------------------------
// FFN part 1: h = gelu(LN(v) @ W1 + b1)   (f16 out, [M,512])
// ---------------------------------------------------------------------------
__global__ __launch_bounds__(256)
void ffn1(const float* __restrict__ vin,
          const float* __restrict__ ln_g, const float* __restrict__ ln_b,
          const _Float16* __restrict__ wt1, const float* __restrict__ b1,
          _Float16* __restrict__ hout)
{
  __shared__ alignas(16) _Float16 xs[64][136];
  __shared__ alignas(16) _Float16 ws_[128][136];
  const int tid = threadIdx.x;
  const int lane = tid & 63;
  const int w = tid >> 6;
  const int quad = lane >> 4;
  const int l16 = lane & 15;
  const int rowBase = blockIdx.x * 64;

  float gg1 = ln_g[lane], gg2 = ln_g[lane + 64];
  float gb1 = ln_b[lane], gb2 = ln_b[lane + 64];
  for (int r = 0; r < 16; ++r) {
    int row = w * 16 + r;
    ln_row(vin + (size_t)(rowBase + row) * CH, gg1, gg2, gb1, gb2, &xs[row][0], lane);
  }

  half8 xf[4];
  f32x4 acc[8];
  const int rowq = w * 16 + quad * 4;
  bool xfLoaded = false;
  for (int cc = 0; cc < 4; ++cc) {
    __syncthreads();
    stage_w(wt1 + (size_t)cc * 128 * CH, CH, ws_, tid);
    __syncthreads();
    if (!xfLoaded) {
#pragma unroll
      for (int kt = 0; kt < 4; ++kt)
        xf[kt] = *(const half8*)&xs[w * 16 + l16][kt * 32 + quad * 8];
      xfLoaded = true;
    }
    mm8_lds(xf, ws_, l16, quad, acc);
#pragma unroll
    for (int nt = 0; nt < 8; ++nt) {
      int col = cc * 128 + nt * 16 + l16;
      float bv = b1[col];
#pragma unroll
      for (int r = 0; r < 4; ++r)
        hout[(size_t)(rowBase + rowq + r) * FFD + col] = (_Float16)(gelu_(acc[nt][r] + bv));
    }
  }
}

// ---------------------------------------------------------------------------
// FFN part 2: v += h @ W2 + b2
// ---------------------------------------------------------------------------
__global__ __launch_bounds__(256)
void ffn2(const _Float16* __restrict__ h,
          const _Float16* __restrict__ wt2, const float* __restrict__ b2,
          float* __restrict__ vio)
{
  __shared__ alignas(16) _Float16 ws_[128][136];
  const int tid = threadIdx.x;
  const int lane = tid & 63;
  const int w = tid >> 6;
  const int quad = lane >> 4;
  const int l16 = lane & 15;
  const int rowBase = blockIdx.x * 64;

  f32x4 acc[8];
  const f32x4 fzero = {0.0f, 0.0f, 0.0f, 0.0f};
#pragma unroll
  for (int nt = 0; nt < 8; ++nt) acc[nt] = fzero;

  for (int kc = 0; kc < 4; ++kc) {
    __syncthreads();
    stage_w(wt2 + kc * 128, FFD, ws_, tid);   // rows=cout(128), k-slice kc*128..+128
    __syncthreads();
#pragma unroll
    for (int kt = 0; kt < 4; ++kt) {
      half8 hf = *(const half8*)(h + (size_t)(rowBase + w * 16 + l16) * FFD + kc * 128 + kt * 32 + quad * 8);
#pragma unroll
      for (int nt = 0; nt < 8; ++nt) {
        half8 wf = *(const half8*)&ws_[nt * 16 + l16][kt * 32 + quad * 8];
        acc[nt] = __builtin_amdgcn_mfma_f32_16x16x32_f16(hf, wf, acc[nt], 0, 0, 0);
      }
    }
  }
  const int rowq = w * 16 + quad * 4;
#pragma unroll
  for (int nt = 0; nt < 8; ++nt) {
    int col = nt * 16 + l16;
    float bv = b2[col];
#pragma unroll
    for (int r = 0; r < 4; ++r)
      vio[(size_t)(rowBase + rowq + r) * CH + col] += acc[nt][r] + bv;
  }
}

// ---------------------------------------------------------------------------
// final: s = v + transpose(v); e = s@decW + decb; write dense row (zeros + 12)
// ---------------------------------------------------------------------------
__global__ __launch_bounds__(256)
void decode_row(const float* __restrict__ vin, const int* __restrict__ tidx,
                const int* __restrict__ nbr, const float* __restrict__ decW,
                const float* __restrict__ decB, float* __restrict__ out)
{
  __shared__ float ev[KNN];
  __shared__ int nbr_s[KNN];
  const int n = blockIdx.x;
  const int tid = threadIdx.x;
  const int lane = tid & 63;
  const int w = tid >> 6;
  if (tid < KNN) nbr_s[tid] = nbr[n * KNN + tid];
  float dw1 = decW[lane], dw2 = decW[lane + 64];
  for (int k = w; k < KNN; k += 4) {
    int e = n * KNN + k;
    int ti = tidx[e];
    float s1 = vin[(size_t)e * CH + lane];
    float s2 = vin[(size_t)e * CH + 64 + lane];
    if (ti >= 0) {
      s1 += vin[(size_t)ti * CH + lane];
      s2 += vin[(size_t)ti * CH + 64 + lane];
    }
    float tot = wave_sum(s1 * dw1 + s2 * dw2);
    if (lane == 0) ev[k] = tot + decB[0];
  }
  __syncthreads();
  float4 z = make_float4(0.f, 0.f, 0.f, 0.f);
  float4* row = (float4*)(out + (size_t)n * NPTS);
  for (int idx = tid; idx < NPTS / 4; idx += 256) row[idx] = z;
  __syncthreads();
  if (tid < KNN) out[(size_t)n * NPTS + nbr_s[tid]] = ev[tid];
}

// ---------------------------------------------------------------------------
extern "C" void kernel_launch(void* const* d_in, const int* in_sizes, int n_in,
                              void* d_out, int out_size, void* d_ws, size_t ws_size,
                              hipStream_t stream)
{
  (void)in_sizes; (void)n_in; (void)out_size; (void)ws_size;
  const float* coords  = (const float*)d_in[0];
  const float* t_ln_g  = (const float*)d_in[1];
  const float* t_ln_b  = (const float*)d_in[2];
  const float* t_Wa    = (const float*)d_in[3];
  const float* t_ba    = (const float*)d_in[4];
  const float* t_Wga   = (const float*)d_in[5];
  const float* t_bga   = (const float*)d_in[6];
  const float* t_Wb    = (const float*)d_in[7];
  const float* t_bb    = (const float*)d_in[8];
  const float* t_Wgb   = (const float*)d_in[9];
  const float* t_bgb   = (const float*)d_in[10];
  const float* t_Wo    = (const float*)d_in[11];
  const float* t_bo    = (const float*)d_in[12];
  const float* t_Wgo   = (const float*)d_in[13];
  const float* t_bgo   = (const float*)d_in[14];
  const float* t_lno_g = (const float*)d_in[15];
  const float* t_lno_b = (const float*)d_in[16];
  const float* f_ln_g  = (const float*)d_in[17];
  const float* f_ln_b  = (const float*)d_in[18];
  const float* f_W1    = (const float*)d_in[19];
  const float* f_b1    = (const float*)d_in[20];
  const float* f_W2    = (const float*)d_in[21];
  const float* f_b2    = (const float*)d_in[22];
  const float* dec_W   = (const float*)d_in[23];
  const float* dec_b   = (const float*)d_in[24];

  const size_t NKC = (size_t)MEDGE * CH;   // 12,582,912
  char* ws = (char*)d_ws;
  float* v    = (float*)(ws);
  float* kbuf = (float*)(ws + NKC * 4);
  int* nbr    = (int*)(ws + NKC * 8);
  int* tidx   = (int*)(ws + NKC * 8 + (size_t)MEDGE * 4);
  _Float16* wbase = (_Float16*)(ws + NKC * 8 + (size_t)MEDGE * 8);
  const size_t WTRI = (size_t)12 * CH * CH;
  _Float16* wA  = wbase;
  _Float16* wGA = wA  + WTRI;
  _Float16* wB  = wGA + WTRI;
  _Float16* wGB = wB  + WTRI;
  _Float16* wGO = wGB + WTRI;
  _Float16* wO  = wGO + WTRI;
  _Float16* w1  = wO  + WTRI;
  _Float16* w2  = w1  + (size_t)6 * FFD * CH;

  // scratch inside d_out (free until decode_row rewrites it)
  _Float16* abuf  = (_Float16*)d_out;
  _Float16* bbuf  = abuf + NKC;
  _Float16* gobuf = bbuf + NKC;
  _Float16* hbuf  = gobuf + NKC;   // [MEDGE][512] f16

  // weight prep
  transpose_cast<<<768, 256, 0, stream>>>(t_Wa,  wA,  12, CH, CH);
  transpose_cast<<<768, 256, 0, stream>>>(t_Wga, wGA, 12, CH, CH);
  transpose_cast<<<768, 256, 0, stream>>>(t_Wb,  wB,  12, CH, CH);
  transpose_cast<<<768, 256, 0, stream>>>(t_Wgb, wGB, 12, CH, CH);
  transpose_cast<<<768, 256, 0, stream>>>(t_Wgo, wGO, 12, CH, CH);
  transpose_cast<<<768, 256, 0, stream>>>(t_Wo,  wO,  12, CH, CH);
  transpose_cast<<<1536, 256, 0, stream>>>(f_W1, w1, 6, CH, FFD);
  transpose_cast<<<1536, 256, 0, stream>>>(f_W2, w2, 6, FFD, CH);

  knn_embed<<<NPTS, 256, 0, stream>>>(coords, nbr, v);
  build_tidx<<<MEDGE / 256, 256, 0, stream>>>(nbr, tidx);

  for (int l = 0; l < 6; ++l) {
    for (int rc = 0; rc < 2; ++rc) {
      int s = l * 2 + rc;
      ln_gemm5<<<MEDGE / 64, 256, 0, stream>>>(v,
          t_ln_g + s * CH, t_ln_b + s * CH,
          wA  + (size_t)s * CH * CH, t_ba  + s * CH,
          wGA + (size_t)s * CH * CH, t_bga + s * CH,
          wB  + (size_t)s * CH * CH, t_bb  + s * CH,
          wGB + (size_t)s * CH * CH, t_bgb + s * CH,
          wGO + (size_t)s * CH * CH, t_bgo + s * CH,
          abuf, bbuf, gobuf);
      tri_einsum<<<NPTS, 256, 0, stream>>>(abuf, bbuf, nbr, tidx, kbuf, rc);
      ln_out_gate<<<MEDGE / 64, 256, 0, stream>>>(kbuf,
          t_lno_g + s * CH, t_lno_b + s * CH,
          wO + (size_t)s * CH * CH, t_bo + s * CH, gobuf, v);
    }
    ffn1<<<MEDGE / 64, 256, 0, stream>>>(v, f_ln_g + l * CH, f_ln_b + l * CH,
        w1 + (size_t)l * FFD * CH, f_b1 + l * FFD, hbuf);
    ffn2<<<MEDGE / 64, 256, 0, stream>>>(hbuf, w2 + (size_t)l * FFD * CH,
        f_b2 + l * CH, v);
  }

  decode_row<<<NPTS, 256, 0, stream>>>(v, tidx, nbr, dec_W, dec_b, (float*)d_out);
}